// Round 2
// baseline (2510.511 us; speedup 1.0000x reference)
//
#include <hip/hip_runtime.h>
#include <hip/hip_bf16.h>

// Problem constants
#define B_    16384
#define NV_   32
#define NF_   64
#define AOD_  64
#define SD_   512
#define H_    2048
#define MC_   4096      // batch chunk (4 chunks)
#define NCHUNK_ 4

typedef __attribute__((ext_vector_type(8))) short short8_t;
typedef __attribute__((ext_vector_type(8))) unsigned short ushort8_t;
typedef __attribute__((ext_vector_type(4))) unsigned short ushort4_t;
typedef __attribute__((ext_vector_type(4))) float f32x4;

__device__ __forceinline__ float bf2f(unsigned short u) {
  union { unsigned int i; float f; } c; c.i = ((unsigned int)u) << 16; return c.f;
}
__device__ __forceinline__ unsigned short f2bf(float f) {
  union { float f; unsigned int i; } c; c.f = f;
  unsigned int x = c.i;
  return (unsigned short)((x + 0x7FFFu + ((x >> 16) & 1u)) >> 16);  // RNE
}

__device__ __forceinline__ void gload16(const unsigned short* g, unsigned short* l) {
  __builtin_amdgcn_global_load_lds(
      (const __attribute__((address_space(1))) unsigned int*)g,
      (__attribute__((address_space(3))) unsigned int*)l, 16, 0, 0);
}

// ---------------- prep kernels ----------------

// W[K][N] f32 -> hi/lo bf16 planes of W^T: dst*[N][K]
__global__ __launch_bounds__(256) void transpose_split(
    const float* __restrict__ src, unsigned short* __restrict__ dhi,
    unsigned short* __restrict__ dlo, int K, int N) {
  __shared__ float tile[32][33];
  const int nb = blockIdx.x * 32, kb = blockIdx.y * 32;
  const int tx = threadIdx.x & 31, ty = threadIdx.x >> 5;
#pragma unroll
  for (int r = 0; r < 32; r += 8)
    tile[ty + r][tx] = src[(size_t)(kb + ty + r) * N + nb + tx];
  __syncthreads();
#pragma unroll
  for (int r = 0; r < 32; r += 8) {
    const float x = tile[tx][ty + r];
    const unsigned short h = f2bf(x);
    const size_t o = (size_t)(nb + ty + r) * K + kb + tx;
    dhi[o] = h;
    dlo[o] = f2bf(x - bf2f(h));
  }
}

// W[K][N] f32 -> W^T[N][K] bf16 single plane
__global__ __launch_bounds__(256) void transpose_single(
    const float* __restrict__ src, unsigned short* __restrict__ dst, int K, int N) {
  __shared__ float tile[32][33];
  const int nb = blockIdx.x * 32, kb = blockIdx.y * 32;
  const int tx = threadIdx.x & 31, ty = threadIdx.x >> 5;
#pragma unroll
  for (int r = 0; r < 32; r += 8)
    tile[ty + r][tx] = src[(size_t)(kb + ty + r) * N + nb + tx];
  __syncthreads();
#pragma unroll
  for (int r = 0; r < 32; r += 8)
    dst[(size_t)(nb + ty + r) * K + kb + tx] = f2bf(tile[tx][ty + r]);
}

// f32 -> hi/lo bf16 planes (flat)
__global__ __launch_bounds__(256) void cvt_split(
    const float* __restrict__ in, unsigned short* __restrict__ hi,
    unsigned short* __restrict__ lo) {
  const int i = (blockIdx.x * 256 + threadIdx.x) * 4;
  const float4 v = *(const float4*)(in + i);
  ushort4_t oh, ol;
  oh.x = f2bf(v.x); ol.x = f2bf(v.x - bf2f(oh.x));
  oh.y = f2bf(v.y); ol.y = f2bf(v.y - bf2f(oh.y));
  oh.z = f2bf(v.z); ol.z = f2bf(v.z - bf2f(oh.z));
  oh.w = f2bf(v.w); ol.w = f2bf(v.w - bf2f(oh.w));
  *(ushort4_t*)(hi + i) = oh;
  *(ushort4_t*)(lo + i) = ol;
}

// ---------------- split-bf16 GEMM ----------------
// C[M,N] = A[M,K] * Bt[N,K]^T + bias, with A/B optionally split (hi+lo planes).
// Split path computes Ah*Bh + Ah*Bl + Al*Bh (fp32-emulation, rel err ~2e-5).
// OMODE: 0 = bf16 out, 1 = bf16+ReLU, 2 = split bf16 pair + ReLU, 3 = f32 out.
template <int ASPLIT, int BSPLIT, int OMODE>
__global__ __launch_bounds__(256) void gemm_k(
    const unsigned short* __restrict__ Ah, const unsigned short* __restrict__ Al, int lda,
    const unsigned short* __restrict__ Bh, const unsigned short* __restrict__ Bl,
    const float* __restrict__ bias,
    void* __restrict__ outH, void* __restrict__ outL, int N, int K) {
  __shared__ unsigned short lAh[128 * 32];
  __shared__ unsigned short lBh[128 * 32];
  __shared__ unsigned short lAl[ASPLIT ? 128 * 32 : 64];
  __shared__ unsigned short lBl[BSPLIT ? 128 * 32 : 64];

  const int t = threadIdx.x;
  const int w = t >> 6, l = t & 63;
  const int wm = w >> 1, wn = w & 1;
  const int lhi = l >> 4, llo = l & 15;
  const int k8 = lhi * 8;
  const int m0 = blockIdx.y * 128, n0 = blockIdx.x * 128;

  const int r1 = t >> 2, kc = (t & 3) * 8;
  const size_t aoff1 = (size_t)(m0 + r1) * lda + kc;
  const size_t aoff2 = (size_t)(m0 + r1 + 64) * lda + kc;
  const size_t boff1 = (size_t)(n0 + r1) * (size_t)K + kc;
  const size_t boff2 = (size_t)(n0 + r1 + 64) * (size_t)K + kc;
  unsigned short* const d1 = (unsigned short*)0 + w * 512;       // symbolic: per-wave LDS offsets
  const int wo1 = w * 512, wo2 = 2048 + w * 512;
  (void)d1;

  f32x4 acc[4][4];
#pragma unroll
  for (int i = 0; i < 4; ++i)
#pragma unroll
    for (int j = 0; j < 4; ++j) acc[i][j] = (f32x4){0.f, 0.f, 0.f, 0.f};

  for (int kt = 0; kt < K; kt += 32) {
    gload16(Ah + aoff1 + kt, lAh + wo1);
    gload16(Ah + aoff2 + kt, lAh + wo2);
    if constexpr (ASPLIT) {
      gload16(Al + aoff1 + kt, lAl + wo1);
      gload16(Al + aoff2 + kt, lAl + wo2);
    }
    gload16(Bh + boff1 + kt, lBh + wo1);
    gload16(Bh + boff2 + kt, lBh + wo2);
    if constexpr (BSPLIT) {
      gload16(Bl + boff1 + kt, lBl + wo1);
      gload16(Bl + boff2 + kt, lBl + wo2);
    }
    __syncthreads();  // drains vmcnt(0): staged data visible

    short8_t ah[4], bh[4];
#pragma unroll
    for (int i = 0; i < 4; ++i)
      ah[i] = *(const short8_t*)&lAh[(wm * 64 + i * 16 + llo) * 32 + k8];
#pragma unroll
    for (int j = 0; j < 4; ++j)
      bh[j] = *(const short8_t*)&lBh[(wn * 64 + j * 16 + llo) * 32 + k8];

    if constexpr (ASPLIT && BSPLIT) {
      short8_t al[4], bl[4];
#pragma unroll
      for (int i = 0; i < 4; ++i)
        al[i] = *(const short8_t*)&lAl[(wm * 64 + i * 16 + llo) * 32 + k8];
#pragma unroll
      for (int j = 0; j < 4; ++j)
        bl[j] = *(const short8_t*)&lBl[(wn * 64 + j * 16 + llo) * 32 + k8];
#pragma unroll
      for (int i = 0; i < 4; ++i)
#pragma unroll
        for (int j = 0; j < 4; ++j) {
          acc[i][j] = __builtin_amdgcn_mfma_f32_16x16x32_bf16(ah[i], bh[j], acc[i][j], 0, 0, 0);
          acc[i][j] = __builtin_amdgcn_mfma_f32_16x16x32_bf16(ah[i], bl[j], acc[i][j], 0, 0, 0);
          acc[i][j] = __builtin_amdgcn_mfma_f32_16x16x32_bf16(al[i], bh[j], acc[i][j], 0, 0, 0);
        }
    } else {
#pragma unroll
      for (int i = 0; i < 4; ++i)
#pragma unroll
        for (int j = 0; j < 4; ++j)
          acc[i][j] = __builtin_amdgcn_mfma_f32_16x16x32_bf16(ah[i], bh[j], acc[i][j], 0, 0, 0);
    }
    __syncthreads();  // all waves done reading before next stage overwrites
  }

  // epilogue: C/D layout col = lane&15, row = (lane>>4)*4 + reg
#pragma unroll
  for (int j = 0; j < 4; ++j) {
    const int col = n0 + wn * 64 + j * 16 + llo;
    const float bv = bias[col];
#pragma unroll
    for (int i = 0; i < 4; ++i) {
      const int row = m0 + wm * 64 + i * 16 + lhi * 4;
#pragma unroll
      for (int r = 0; r < 4; ++r) {
        float v = acc[i][j][r] + bv;
        if constexpr (OMODE == 1 || OMODE == 2) v = fmaxf(v, 0.f);
        const size_t o = (size_t)(row + r) * N + col;
        if constexpr (OMODE == 3) {
          ((float*)outH)[o] = v;
        } else if constexpr (OMODE == 2) {
          const unsigned short h = f2bf(v);
          ((unsigned short*)outH)[o] = h;
          ((unsigned short*)outL)[o] = f2bf(v - bf2f(h));
        } else {
          ((unsigned short*)outH)[o] = f2bf(v);
        }
      }
    }
  }
}

// ---------------- mixing: per-batch small matmuls + ELU + absmax norm + sigmoid ----------------
__global__ __launch_bounds__(256) void mixing_kernel(
    const float* __restrict__ emb,            // [MC,32,64] f32 (chunk-offset)
    const float* __restrict__ w1buf,          // [MC,2048] f32 = [64][32]
    const unsigned short* __restrict__ b1buf, // [MC,1024] bf16 = [32][32]
    const float* __restrict__ w2buf,          // [MC,2048] f32 = [32][64]
    const unsigned short* __restrict__ b2buf, // [MC,2048] bf16 = [32][64]
    float* __restrict__ out) {                // [MC,32,64] f32 (chunk-offset)
  __shared__ float s_emb[2048];
  __shared__ float s_w1[2048];
  __shared__ float s_b1[1024];
  __shared__ float s_w2[2048];
  __shared__ float s_b2[2048];
  __shared__ float s_hid[1024];
  __shared__ float s_out[2048];
  __shared__ float s_norm[64];

  const int b = blockIdx.x, t = threadIdx.x;

  {
    const float4* src = (const float4*)(emb + (size_t)b * 2048);
    ((float4*)s_emb)[t] = src[t];
    ((float4*)s_emb)[t + 256] = src[t + 256];
  }
  {
    const float4* src = (const float4*)(w1buf + (size_t)b * 2048);
    ((float4*)s_w1)[t] = src[t];
    ((float4*)s_w1)[t + 256] = src[t + 256];
  }
  {
    const float4* src = (const float4*)(w2buf + (size_t)b * 2048);
    ((float4*)s_w2)[t] = src[t];
    ((float4*)s_w2)[t + 256] = src[t + 256];
  }
  if (t < 128) {
    ushort8_t u = *(const ushort8_t*)(b1buf + (size_t)b * 1024 + t * 8);
#pragma unroll
    for (int e = 0; e < 8; ++e) s_b1[t * 8 + e] = bf2f(u[e]);
  }
  {
    ushort8_t u = *(const ushort8_t*)(b2buf + (size_t)b * 2048 + t * 8);
#pragma unroll
    for (int e = 0; e < 8; ++e) s_b2[t * 8 + e] = bf2f(u[e]);
  }
  __syncthreads();

  // hidden[v][h] = elu( sum_a emb[v][a] * w1[a][h] + b1[v][h] )
#pragma unroll
  for (int p = 0; p < 4; ++p) {
    const int idx = t + p * 256;          // 0..1023
    const int v = idx >> 5, h = idx & 31;
    float acc = s_b1[idx];
#pragma unroll 8
    for (int a = 0; a < 64; ++a) acc += s_emb[v * 64 + a] * s_w1[a * 32 + h];
    s_hid[idx] = acc > 0.f ? acc : expm1f(acc);
  }
  __syncthreads();

  // outv[v][f] = sum_h hid[v][h] * w2[h][f] + b2[v][f]
#pragma unroll
  for (int p = 0; p < 8; ++p) {
    const int idx = t + p * 256;          // 0..2047
    const int v = idx >> 6, f = idx & 63;
    float acc = s_b2[idx];
#pragma unroll 8
    for (int h = 0; h < 32; ++h) acc += s_hid[v * 32 + h] * s_w2[h * 64 + f];
    s_out[idx] = acc;
  }
  __syncthreads();

  if (t < 64) {
    float m = 0.f;
#pragma unroll
    for (int v = 0; v < 32; ++v) m = fmaxf(m, fabsf(s_out[v * 64 + t]));
    m += 1e-5f;
    s_norm[t] = fminf(1.0f, 5.0f / m);
  }
  __syncthreads();

#pragma unroll
  for (int p = 0; p < 8; ++p) {
    const int idx = t + p * 256;
    const float x = s_out[idx] * s_norm[idx & 63];
    out[(size_t)b * 2048 + idx] = 1.f / (1.f + expf(-x));
  }
}

// ---------------- launch ----------------

extern "C" void kernel_launch(void* const* d_in, const int* in_sizes, int n_in,
                              void* d_out, int out_size, void* d_ws, size_t ws_size,
                              hipStream_t stream) {
  const float* agent_emb = (const float*)d_in[0];
  const float* states    = (const float*)d_in[1];
  const float* w1a_W = (const float*)d_in[2];  const float* w1a_b = (const float*)d_in[3];
  const float* w1b_W = (const float*)d_in[4];  const float* w1b_b = (const float*)d_in[5];
  const float* b1_W  = (const float*)d_in[6];  const float* b1_b  = (const float*)d_in[7];
  const float* w2a_W = (const float*)d_in[8];  const float* w2a_b = (const float*)d_in[9];
  const float* w2b_W = (const float*)d_in[10]; const float* w2b_b = (const float*)d_in[11];
  const float* b2a_W = (const float*)d_in[12]; const float* b2a_b = (const float*)d_in[13];
  const float* b2b_W = (const float*)d_in[14]; const float* b2b_b = (const float*)d_in[15];
  float* out = (float*)d_out;

  char* ws = (char*)d_ws;
  size_t off = 0;
  auto alloc = [&](size_t bytes) -> char* {
    char* p = ws + off;
    off = (off + bytes + 255) & ~(size_t)255;
    return p;
  };
  typedef unsigned short us;
  // states, split (full batch)
  us* sth = (us*)alloc((size_t)B_ * SD_ * 2);
  us* stl = (us*)alloc((size_t)B_ * SD_ * 2);
  // stage-1 weights^T, split
  us* w1aTh = (us*)alloc((size_t)2048 * 512 * 2); us* w1aTl = (us*)alloc((size_t)2048 * 512 * 2);
  us* b1Th  = (us*)alloc((size_t)1024 * 512 * 2); us* b1Tl  = (us*)alloc((size_t)1024 * 512 * 2);
  us* w2aTh = (us*)alloc((size_t)4096 * 512 * 2); us* w2aTl = (us*)alloc((size_t)4096 * 512 * 2);
  us* b2aTh = (us*)alloc((size_t)1024 * 512 * 2); us* b2aTl = (us*)alloc((size_t)1024 * 512 * 2);
  // stage-2 weights^T
  us* w1bTh = (us*)alloc((size_t)2048 * 2048 * 2); us* w1bTl = (us*)alloc((size_t)2048 * 2048 * 2);
  us* w2bTh = (us*)alloc((size_t)2048 * 4096 * 2); us* w2bTl = (us*)alloc((size_t)2048 * 4096 * 2);
  us* b2bT  = (us*)alloc((size_t)2048 * 1024 * 2);
  // per-chunk intermediates (reused across chunks)
  us* t1h = (us*)alloc((size_t)MC_ * 2048 * 2); us* t1l = (us*)alloc((size_t)MC_ * 2048 * 2);
  us* t2h = (us*)alloc((size_t)MC_ * 4096 * 2); us* t2l = (us*)alloc((size_t)MC_ * 4096 * 2);
  us* b1buf = (us*)alloc((size_t)MC_ * 1024 * 2);
  us* t3buf = (us*)alloc((size_t)MC_ * 1024 * 2);
  float* w1buf = (float*)alloc((size_t)MC_ * 2048 * 4);
  float* w2buf = (float*)alloc((size_t)MC_ * 2048 * 4);
  us* b2buf = (us*)alloc((size_t)MC_ * 2048 * 2);
  if (off > ws_size) return;  // workspace too small: bail (output stays poisoned)

  // --- prep ---
  cvt_split<<<(B_ * SD_) / (4 * 256), 256, 0, stream>>>(states, sth, stl);
  transpose_split<<<dim3(2048 / 32, 512 / 32), 256, 0, stream>>>(w1a_W, w1aTh, w1aTl, 512, 2048);
  transpose_split<<<dim3(1024 / 32, 512 / 32), 256, 0, stream>>>(b1_W,  b1Th,  b1Tl,  512, 1024);
  transpose_split<<<dim3(4096 / 32, 512 / 32), 256, 0, stream>>>(w2a_W, w2aTh, w2aTl, 512, 4096);
  transpose_split<<<dim3(1024 / 32, 512 / 32), 256, 0, stream>>>(b2a_W, b2aTh, b2aTl, 512, 1024);
  transpose_split<<<dim3(2048 / 32, 2048 / 32), 256, 0, stream>>>(w1b_W, w1bTh, w1bTl, 2048, 2048);
  transpose_split<<<dim3(2048 / 32, 4096 / 32), 256, 0, stream>>>(w2b_W, w2bTh, w2bTl, 4096, 2048);
  transpose_single<<<dim3(2048 / 32, 1024 / 32), 256, 0, stream>>>(b2b_W, b2bT, 1024, 2048);

  for (int c = 0; c < NCHUNK_; ++c) {
    const size_t R = (size_t)c * MC_;
    const us* Ah = sth + R * SD_;
    const us* Al = stl + R * SD_;
    // stage 1 (K=512): t1/t2 split+ReLU, b1 plain bf16, t3 bf16+ReLU
    gemm_k<1, 1, 2><<<dim3(16, MC_ / 128), 256, 0, stream>>>(
        Ah, Al, SD_, w1aTh, w1aTl, w1a_b, t1h, t1l, 2048, SD_);
    gemm_k<1, 1, 0><<<dim3(8, MC_ / 128), 256, 0, stream>>>(
        Ah, Al, SD_, b1Th, b1Tl, b1_b, b1buf, nullptr, 1024, SD_);
    gemm_k<1, 1, 2><<<dim3(32, MC_ / 128), 256, 0, stream>>>(
        Ah, Al, SD_, w2aTh, w2aTl, w2a_b, t2h, t2l, 4096, SD_);
    gemm_k<1, 1, 1><<<dim3(8, MC_ / 128), 256, 0, stream>>>(
        Ah, Al, SD_, b2aTh, b2aTl, b2a_b, t3buf, nullptr, 1024, SD_);
    // stage 2: w1 (K=2048) f32 out, w2 (K=4096) f32 out, b2 (K=1024) bf16 out
    gemm_k<1, 1, 3><<<dim3(16, MC_ / 128), 256, 0, stream>>>(
        t1h, t1l, 2048, w1bTh, w1bTl, w1b_b, w1buf, nullptr, 2048, 2048);
    gemm_k<1, 1, 3><<<dim3(16, MC_ / 128), 256, 0, stream>>>(
        t2h, t2l, 4096, w2bTh, w2bTl, w2b_b, w2buf, nullptr, 2048, 4096);
    gemm_k<0, 0, 0><<<dim3(16, MC_ / 128), 256, 0, stream>>>(
        t3buf, nullptr, 1024, b2bT, nullptr, b2b_b, b2buf, nullptr, 2048, 1024);
    // mixing
    mixing_kernel<<<MC_, 256, 0, stream>>>(
        agent_emb + R * 2048, w1buf, b1buf, w2buf, b2buf, out + R * 2048);
  }
}

// Round 4
// 2334.209 us; speedup vs baseline: 1.0755x; 1.0755x over previous
//
#include <hip/hip_runtime.h>
#include <hip/hip_bf16.h>

// Problem constants
#define B_    16384
#define NV_   32
#define NF_   64
#define AOD_  64
#define SD_   512
#define H_    2048
#define MC_   8192      // batch chunk (2 chunks)
#define NCHUNK_ 2

typedef unsigned short us;
typedef __attribute__((ext_vector_type(8))) short short8_t;
typedef __attribute__((ext_vector_type(8))) unsigned short ushort8_t;
typedef __attribute__((ext_vector_type(4))) unsigned short ushort4_t;
typedef __attribute__((ext_vector_type(4))) float f32x4;

__device__ __forceinline__ float bf2f(us u) {
  union { unsigned int i; float f; } c; c.i = ((unsigned int)u) << 16; return c.f;
}
__device__ __forceinline__ us f2bf(float f) {
  union { float f; unsigned int i; } c; c.f = f;
  unsigned int x = c.i;
  return (us)((x + 0x7FFFu + ((x >> 16) & 1u)) >> 16);  // RNE
}

__device__ __forceinline__ void gload16(const us* g, us* l) {
  __builtin_amdgcn_global_load_lds(
      (const __attribute__((address_space(1))) unsigned int*)g,
      (__attribute__((address_space(3))) unsigned int*)l, 16, 0, 0);
}

// ---------------- prep kernels ----------------

// W[K][N] f32 -> hi/lo bf16 planes of W^T: dst*[N][K]
__global__ __launch_bounds__(256) void transpose_split(
    const float* __restrict__ src, us* __restrict__ dhi,
    us* __restrict__ dlo, int K, int N) {
  __shared__ float tile[32][33];
  const int nb = blockIdx.x * 32, kb = blockIdx.y * 32;
  const int tx = threadIdx.x & 31, ty = threadIdx.x >> 5;
#pragma unroll
  for (int r = 0; r < 32; r += 8)
    tile[ty + r][tx] = src[(size_t)(kb + ty + r) * N + nb + tx];
  __syncthreads();
#pragma unroll
  for (int r = 0; r < 32; r += 8) {
    const float x = tile[tx][ty + r];
    const us h = f2bf(x);
    const size_t o = (size_t)(nb + ty + r) * K + kb + tx;
    dhi[o] = h;
    dlo[o] = f2bf(x - bf2f(h));
  }
}

// W[K][N] f32 -> W^T[N][K] bf16 single plane
__global__ __launch_bounds__(256) void transpose_single(
    const float* __restrict__ src, us* __restrict__ dst, int K, int N) {
  __shared__ float tile[32][33];
  const int nb = blockIdx.x * 32, kb = blockIdx.y * 32;
  const int tx = threadIdx.x & 31, ty = threadIdx.x >> 5;
#pragma unroll
  for (int r = 0; r < 32; r += 8)
    tile[ty + r][tx] = src[(size_t)(kb + ty + r) * N + nb + tx];
  __syncthreads();
#pragma unroll
  for (int r = 0; r < 32; r += 8)
    dst[(size_t)(nb + ty + r) * K + kb + tx] = f2bf(tile[tx][ty + r]);
}

// f32 -> hi/lo bf16 planes (flat)
__global__ __launch_bounds__(256) void cvt_split(
    const float* __restrict__ in, us* __restrict__ hi, us* __restrict__ lo) {
  const int i = (blockIdx.x * 256 + threadIdx.x) * 4;
  const float4 v = *(const float4*)(in + i);
  ushort4_t oh, ol;
  oh.x = f2bf(v.x); ol.x = f2bf(v.x - bf2f(oh.x));
  oh.y = f2bf(v.y); ol.y = f2bf(v.y - bf2f(oh.y));
  oh.z = f2bf(v.z); ol.z = f2bf(v.z - bf2f(oh.z));
  oh.w = f2bf(v.w); ol.w = f2bf(v.w - bf2f(oh.w));
  *(ushort4_t*)(hi + i) = oh;
  *(ushort4_t*)(lo + i) = ol;
}

// ---------------- 256x256 ring-4 GEMM ----------------
// C[M,N] = A*B^T + bias where split mode computes Ah*Bh + Al*Bh + Ah*Bl via a
// 3-segment K' loop (wave-uniform plane select per K-tile) -> plain 2-operand
// schedule. BK=32, 8 waves (2Mx4N), LDS ring of 4 buffers (32KB each, 128KB
// dynamic). Counted vmcnt(8) (2 tiles in flight), raw s_barrier (no drain),
// stage t+3 issued at iter start (writes buf of t-1, readers done at barrier).
// LDS XOR swizzle ((row&3)<<4) applied on BOTH sides: pre-swizzled global src
// for global_load_lds (linear dest) + swizzled ds_read addr.
// OMODE: 0 = bf16 out, 1 = bf16+ReLU, 2 = split bf16 pair + ReLU, 3 = f32 out.
template <int SPLIT, int OMODE>
__global__ __launch_bounds__(512, 2) void gemm8(
    const us* __restrict__ Ah, const us* __restrict__ Al, int lda,
    const us* __restrict__ Bh, const us* __restrict__ Bl, int ldb,
    const float* __restrict__ bias,
    void* __restrict__ outH, void* __restrict__ outL, int N, int KK, int gx) {
  extern __shared__ __align__(16) char smem[];   // 4 bufs x (A 16KB + B 16KB)

  const int t = threadIdx.x;
  const int w = t >> 6, l = t & 63;
  const int wm = w >> 2, wn = w & 3;
  const int llo = l & 15, lhi = l >> 4;

  // bijective XCD swizzle (m204)
  const int nwg = gridDim.x;
  const int q = nwg >> 3, r = nwg & 7;
  const int xcd = blockIdx.x & 7, idx = blockIdx.x >> 3;
  const int wg = (xcd < r ? xcd * (q + 1) : r * (q + 1) + (xcd - r) * q) + idx;
  const int bx = wg % gx, by = wg / gx;
  const int m0 = by * 256, n0 = bx * 256;

  // staging: thread covers slots {t, t+512} of A-tile and B-tile (16B slots).
  // slot s -> row s>>2, phys chunk s&3; logical chunk = (s&3) ^ (row&3).
  const int s1 = t + 512;
  const int rowA0 = t >> 2, rowA1 = s1 >> 2;
  const int ch0 = (t & 3) ^ (rowA0 & 3), ch1 = (s1 & 3) ^ (rowA1 & 3);
  const size_t aoff0 = (size_t)(m0 + rowA0) * lda + ch0 * 8;
  const size_t aoff1 = (size_t)(m0 + rowA1) * lda + ch1 * 8;
  const size_t boff0 = (size_t)(n0 + rowA0) * ldb + ch0 * 8;
  const size_t boff1 = (size_t)(n0 + rowA1) * ldb + ch1 * 8;
  const int wbase = w * 1024;   // wave's 64 lanes x 16B

  // read offsets (loop-invariant, swizzled)
  int offA[8], offB[4];
#pragma unroll
  for (int i = 0; i < 8; ++i) {
    const int rr = wm * 128 + i * 16 + llo;
    offA[i] = (rr * 64 + lhi * 16) ^ ((llo & 3) << 4);
  }
#pragma unroll
  for (int j = 0; j < 4; ++j) {
    const int rr = wn * 64 + j * 16 + llo;
    offB[j] = ((rr * 64 + lhi * 16) ^ ((llo & 3) << 4)) + 16384;
  }

  const int NT = (SPLIT ? 3 : 1) * (KK / 32);

  auto stage = [&](int tile) {
    int ko;
    const us *As, *Bs;
    if constexpr (SPLIT) {
      const int kt = tile * 32;
      const int seg = (kt >= KK) + (kt >= 2 * KK);
      ko = kt - seg * KK;
      As = (seg == 1) ? Al : Ah;
      Bs = (seg == 2) ? Bl : Bh;
    } else {
      ko = tile * 32; As = Ah; Bs = Bh;
    }
    char* base = smem + (tile & 3) * 32768;
    gload16(As + aoff0 + ko, (us*)(base + wbase));
    gload16(As + aoff1 + ko, (us*)(base + 8192 + wbase));
    gload16(Bs + boff0 + ko, (us*)(base + 16384 + wbase));
    gload16(Bs + boff1 + ko, (us*)(base + 16384 + 8192 + wbase));
  };

  f32x4 acc[8][4];
#pragma unroll
  for (int i = 0; i < 8; ++i)
#pragma unroll
    for (int j = 0; j < 4; ++j) acc[i][j] = (f32x4){0.f, 0.f, 0.f, 0.f};

  // prologue: tiles 0,1,2 -> bufs 0,1,2
  stage(0); stage(1); stage(2);
  asm volatile("s_waitcnt vmcnt(8)" ::: "memory");   // tile0 complete (own)
  __builtin_amdgcn_s_barrier();                      // collectivize
  __builtin_amdgcn_sched_barrier(0);

  for (int tt = 0; tt < NT; ++tt) {
    if (tt + 3 < NT) stage(tt + 3);   // writes buf of tile tt-1 (readers done)
    const char* base = smem + (tt & 3) * 32768;
    short8_t af[8], bf[4];
#pragma unroll
    for (int i = 0; i < 8; ++i) af[i] = *(const short8_t*)(base + offA[i]);
#pragma unroll
    for (int j = 0; j < 4; ++j) bf[j] = *(const short8_t*)(base + offB[j]);
    __builtin_amdgcn_s_setprio(1);
#pragma unroll
    for (int i = 0; i < 8; ++i)
#pragma unroll
      for (int j = 0; j < 4; ++j)
        acc[i][j] = __builtin_amdgcn_mfma_f32_16x16x32_bf16(af[i], bf[j], acc[i][j], 0, 0, 0);
    __builtin_amdgcn_s_setprio(0);
    asm volatile("s_waitcnt vmcnt(8)" ::: "memory");  // tile tt+1 complete (own)
    __builtin_amdgcn_s_barrier();                     // collectivize; buf[tt] free
    __builtin_amdgcn_sched_barrier(0);
  }

  // epilogue: C/D layout col = lane&15, row = (lane>>4)*4 + reg
#pragma unroll
  for (int j = 0; j < 4; ++j) {
    const int col = n0 + wn * 64 + j * 16 + llo;
    const float bv = bias[col];
#pragma unroll
    for (int i = 0; i < 8; ++i) {
      const int row = m0 + wm * 128 + i * 16 + lhi * 4;
#pragma unroll
      for (int rr = 0; rr < 4; ++rr) {
        float v = acc[i][j][rr] + bv;
        if constexpr (OMODE == 1 || OMODE == 2) v = fmaxf(v, 0.f);
        const size_t o = (size_t)(row + rr) * N + col;
        if constexpr (OMODE == 3) {
          ((float*)outH)[o] = v;
        } else if constexpr (OMODE == 2) {
          const us h = f2bf(v);
          ((us*)outH)[o] = h;
          ((us*)outL)[o] = f2bf(v - bf2f(h));
        } else {
          ((us*)outH)[o] = f2bf(v);
        }
      }
    }
  }
}

// ---------------- mixing: register-tiled small matmuls + ELU + absmax norm + sigmoid ----------------
__global__ __launch_bounds__(256) void mixing_kernel(
    const float* __restrict__ emb,      // [MC,32,64] f32
    const float* __restrict__ w1buf,    // [MC,2048] f32 = [64][32]
    const us* __restrict__ b1buf,       // [MC,1024] bf16 = [32][32]
    const float* __restrict__ w2buf,    // [MC,2048] f32 = [32][64]
    const us* __restrict__ b2buf,       // [MC,2048] bf16 = [32][64]
    float* __restrict__ out) {          // [MC,32,64] f32
  __shared__ float s_emb[32 * 65];      // padded rows: bank-spread
  __shared__ float s_w1[2048];
  __shared__ float s_b1[1024];
  __shared__ float s_w2[2048];
  __shared__ float s_b2[2048];
  __shared__ float s_hid[32 * 33];      // padded
  __shared__ float s_out[2048];
  __shared__ float s_norm[64];

  const int b = blockIdx.x, t = threadIdx.x;

  {
    const float4* src = (const float4*)(emb + (size_t)b * 2048);
#pragma unroll
    for (int p = 0; p < 2; ++p) {
      const int i4 = t + p * 256;
      const float4 v = src[i4];
      const int e = i4 * 4;
      *(float4*)&s_emb[(e >> 6) * 65 + (e & 63)] = v;
    }
  }
  {
    const float4* src = (const float4*)(w1buf + (size_t)b * 2048);
    ((float4*)s_w1)[t] = src[t];
    ((float4*)s_w1)[t + 256] = src[t + 256];
  }
  {
    const float4* src = (const float4*)(w2buf + (size_t)b * 2048);
    ((float4*)s_w2)[t] = src[t];
    ((float4*)s_w2)[t + 256] = src[t + 256];
  }
  if (t < 128) {
    ushort8_t u = *(const ushort8_t*)(b1buf + (size_t)b * 1024 + t * 8);
#pragma unroll
    for (int e = 0; e < 8; ++e) s_b1[t * 8 + e] = bf2f(u[e]);
  }
  {
    ushort8_t u = *(const ushort8_t*)(b2buf + (size_t)b * 2048 + t * 8);
#pragma unroll
    for (int e = 0; e < 8; ++e) s_b2[t * 8 + e] = bf2f(u[e]);
  }
  __syncthreads();

  // pass1: thread = (v, hq): hidden[v][hq*4..+3] = elu(emb[v,:] @ w1[:,h] + b1)
  {
    const int v = t >> 3, hq = t & 7;
    float a0 = s_b1[v * 32 + hq * 4 + 0];
    float a1 = s_b1[v * 32 + hq * 4 + 1];
    float a2 = s_b1[v * 32 + hq * 4 + 2];
    float a3 = s_b1[v * 32 + hq * 4 + 3];
#pragma unroll 8
    for (int aa = 0; aa < 64; ++aa) {
      const int ai = (aa + hq * 8) & 63;            // stagger: bank-spread
      const float e = s_emb[v * 65 + ai];
      const float4 wv = *(const float4*)&s_w1[ai * 32 + hq * 4];
      a0 += e * wv.x; a1 += e * wv.y; a2 += e * wv.z; a3 += e * wv.w;
    }
    s_hid[v * 33 + hq * 4 + 0] = a0 > 0.f ? a0 : expm1f(a0);
    s_hid[v * 33 + hq * 4 + 1] = a1 > 0.f ? a1 : expm1f(a1);
    s_hid[v * 33 + hq * 4 + 2] = a2 > 0.f ? a2 : expm1f(a2);
    s_hid[v * 33 + hq * 4 + 3] = a3 > 0.f ? a3 : expm1f(a3);
  }
  __syncthreads();

  // pass2: thread = (v, fo): out[v][fo*8..+7] = hid[v,:] @ w2[:,f] + b2
  {
    const int v = t >> 3, fo = t & 7;
    float c[8];
#pragma unroll
    for (int k = 0; k < 8; ++k) c[k] = s_b2[v * 64 + fo * 8 + k];
#pragma unroll 8
    for (int hh = 0; hh < 32; ++hh) {
      const int hi2 = (hh + fo * 4) & 31;           // stagger
      const float hv = s_hid[v * 33 + hi2];
      const float4 w0 = *(const float4*)&s_w2[hi2 * 64 + fo * 8];
      const float4 w1v = *(const float4*)&s_w2[hi2 * 64 + fo * 8 + 4];
      c[0] += hv * w0.x; c[1] += hv * w0.y; c[2] += hv * w0.z; c[3] += hv * w0.w;
      c[4] += hv * w1v.x; c[5] += hv * w1v.y; c[6] += hv * w1v.z; c[7] += hv * w1v.w;
    }
    float4 o0 = {c[0], c[1], c[2], c[3]}, o1 = {c[4], c[5], c[6], c[7]};
    *(float4*)&s_out[v * 64 + fo * 8] = o0;
    *(float4*)&s_out[v * 64 + fo * 8 + 4] = o1;
  }
  __syncthreads();

  if (t < 64) {
    float m = 0.f;
#pragma unroll
    for (int v = 0; v < 32; ++v) m = fmaxf(m, fabsf(s_out[v * 64 + t]));
    m += 1e-5f;
    s_norm[t] = fminf(1.0f, 5.0f / m);
  }
  __syncthreads();

#pragma unroll
  for (int p = 0; p < 8; ++p) {
    const int idx = t + p * 256;
    const float x = s_out[idx] * s_norm[idx & 63];
    out[(size_t)b * 2048 + idx] = 1.f / (1.f + expf(-x));
  }
}

// ---------------- launch ----------------

extern "C" void kernel_launch(void* const* d_in, const int* in_sizes, int n_in,
                              void* d_out, int out_size, void* d_ws, size_t ws_size,
                              hipStream_t stream) {
  const float* agent_emb = (const float*)d_in[0];
  const float* states    = (const float*)d_in[1];
  const float* w1a_W = (const float*)d_in[2];  const float* w1a_b = (const float*)d_in[3];
  const float* w1b_W = (const float*)d_in[4];  const float* w1b_b = (const float*)d_in[5];
  const float* b1_W  = (const float*)d_in[6];  const float* b1_b  = (const float*)d_in[7];
  const float* w2a_W = (const float*)d_in[8];  const float* w2a_b = (const float*)d_in[9];
  const float* w2b_W = (const float*)d_in[10]; const float* w2b_b = (const float*)d_in[11];
  const float* b2a_W = (const float*)d_in[12]; const float* b2a_b = (const float*)d_in[13];
  const float* b2b_W = (const float*)d_in[14]; const float* b2b_b = (const float*)d_in[15];
  float* out = (float*)d_out;

  // allow 128KB dynamic LDS on the gemm instantiations (idempotent, host-side)
  hipFuncSetAttribute((const void*)(gemm8<1, 0>), hipFuncAttributeMaxDynamicSharedMemorySize, 131072);
  hipFuncSetAttribute((const void*)(gemm8<1, 1>), hipFuncAttributeMaxDynamicSharedMemorySize, 131072);
  hipFuncSetAttribute((const void*)(gemm8<1, 2>), hipFuncAttributeMaxDynamicSharedMemorySize, 131072);
  hipFuncSetAttribute((const void*)(gemm8<1, 3>), hipFuncAttributeMaxDynamicSharedMemorySize, 131072);
  hipFuncSetAttribute((const void*)(gemm8<0, 0>), hipFuncAttributeMaxDynamicSharedMemorySize, 131072);

  char* ws = (char*)d_ws;
  size_t off = 0;
  auto alloc = [&](size_t bytes) -> char* {
    char* p = ws + off;
    off = (off + bytes + 255) & ~(size_t)255;
    return p;
  };
  // states, split (full batch)
  us* sth = (us*)alloc((size_t)B_ * SD_ * 2);
  us* stl = (us*)alloc((size_t)B_ * SD_ * 2);
  // stage-1 weights^T, split
  us* w1aTh = (us*)alloc((size_t)2048 * 512 * 2); us* w1aTl = (us*)alloc((size_t)2048 * 512 * 2);
  us* b1Th  = (us*)alloc((size_t)1024 * 512 * 2); us* b1Tl  = (us*)alloc((size_t)1024 * 512 * 2);
  us* w2aTh = (us*)alloc((size_t)4096 * 512 * 2); us* w2aTl = (us*)alloc((size_t)4096 * 512 * 2);
  us* b2aTh = (us*)alloc((size_t)1024 * 512 * 2); us* b2aTl = (us*)alloc((size_t)1024 * 512 * 2);
  // stage-2 weights^T
  us* w1bTh = (us*)alloc((size_t)2048 * 2048 * 2); us* w1bTl = (us*)alloc((size_t)2048 * 2048 * 2);
  us* w2bTh = (us*)alloc((size_t)2048 * 4096 * 2); us* w2bTl = (us*)alloc((size_t)2048 * 4096 * 2);
  us* b2bT  = (us*)alloc((size_t)2048 * 1024 * 2);
  // per-chunk intermediates (reused across chunks)
  us* t1h = (us*)alloc((size_t)MC_ * 2048 * 2); us* t1l = (us*)alloc((size_t)MC_ * 2048 * 2);
  us* t2h = (us*)alloc((size_t)MC_ * 4096 * 2); us* t2l = (us*)alloc((size_t)MC_ * 4096 * 2);
  us* b1buf = (us*)alloc((size_t)MC_ * 1024 * 2);
  us* t3buf = (us*)alloc((size_t)MC_ * 1024 * 2);
  float* w1buf = (float*)alloc((size_t)MC_ * 2048 * 4);
  float* w2buf = (float*)alloc((size_t)MC_ * 2048 * 4);
  us* b2buf = (us*)alloc((size_t)MC_ * 2048 * 2);
  if (off > ws_size) return;  // workspace too small: bail (output stays poisoned)

  // --- prep ---
  cvt_split<<<(B_ * SD_) / (4 * 256), 256, 0, stream>>>(states, sth, stl);
  transpose_split<<<dim3(2048 / 32, 512 / 32), 256, 0, stream>>>(w1a_W, w1aTh, w1aTl, 512, 2048);
  transpose_split<<<dim3(1024 / 32, 512 / 32), 256, 0, stream>>>(b1_W,  b1Th,  b1Tl,  512, 1024);
  transpose_split<<<dim3(4096 / 32, 512 / 32), 256, 0, stream>>>(w2a_W, w2aTh, w2aTl, 512, 4096);
  transpose_split<<<dim3(1024 / 32, 512 / 32), 256, 0, stream>>>(b2a_W, b2aTh, b2aTl, 512, 1024);
  transpose_split<<<dim3(2048 / 32, 2048 / 32), 256, 0, stream>>>(w1b_W, w1bTh, w1bTl, 2048, 2048);
  transpose_split<<<dim3(2048 / 32, 4096 / 32), 256, 0, stream>>>(w2b_W, w2bTh, w2bTl, 4096, 2048);
  transpose_single<<<dim3(2048 / 32, 1024 / 32), 256, 0, stream>>>(b2b_W, b2bT, 1024, 2048);

  for (int c = 0; c < NCHUNK_; ++c) {
    const size_t R = (size_t)c * MC_;
    const us* Ah = sth + R * SD_;
    const us* Al = stl + R * SD_;
    // stage 1 (K=512, split): t1/t2 split+ReLU, b1 plain bf16, t3 bf16+ReLU
    gemm8<1, 2><<<(2048 / 256) * (MC_ / 256), 512, 131072, stream>>>(
        Ah, Al, SD_, w1aTh, w1aTl, SD_, w1a_b, t1h, t1l, 2048, SD_, 2048 / 256);
    gemm8<1, 0><<<(1024 / 256) * (MC_ / 256), 512, 131072, stream>>>(
        Ah, Al, SD_, b1Th, b1Tl, SD_, b1_b, b1buf, nullptr, 1024, SD_, 1024 / 256);
    gemm8<1, 2><<<(4096 / 256) * (MC_ / 256), 512, 131072, stream>>>(
        Ah, Al, SD_, w2aTh, w2aTl, SD_, w2a_b, t2h, t2l, 4096, SD_, 4096 / 256);
    gemm8<1, 1><<<(1024 / 256) * (MC_ / 256), 512, 131072, stream>>>(
        Ah, Al, SD_, b2aTh, b2aTl, SD_, b2a_b, t3buf, nullptr, 1024, SD_, 1024 / 256);
    // stage 2: w1 (K=2048) f32 out, w2 (K=4096) f32 out, b2 (K=1024) bf16 out
    gemm8<1, 3><<<(2048 / 256) * (MC_ / 256), 512, 131072, stream>>>(
        t1h, t1l, 2048, w1bTh, w1bTl, 2048, w1b_b, w1buf, nullptr, 2048, 2048, 2048 / 256);
    gemm8<1, 3><<<(2048 / 256) * (MC_ / 256), 512, 131072, stream>>>(
        t2h, t2l, 4096, w2bTh, w2bTl, 4096, w2b_b, w2buf, nullptr, 2048, 4096, 2048 / 256);
    gemm8<0, 0><<<(2048 / 256) * (MC_ / 256), 512, 131072, stream>>>(
        t3buf, nullptr, 1024, b2bT, nullptr, 1024, b2b_b, b2buf, nullptr, 2048, 1024, 2048 / 256);
    // mixing
    mixing_kernel<<<MC_, 256, 0, stream>>>(
        agent_emb + R * 2048, w1buf, b1buf, w2buf, b2buf, out + R * 2048);
  }
}